// Round 2
// baseline (1139.535 us; speedup 1.0000x reference)
//
#include <hip/hip_runtime.h>

#define NB 4
#define NH 16
#define SEQ 2048
#define DH 128
#define QT 64
#define KT 64
#define NWAVES 4
#define LKSTRIDE (DH + 8)   /* 136 halfs = 272 B row, 16B-aligned, odd dword stride vs banks */
#define LVSTRIDE (KT + 8)   /* 72 halfs = 144 B row, 16B-aligned */
#define LPSTRIDE (KT + 8)

typedef __attribute__((ext_vector_type(8))) _Float16 f16x8;
typedef __attribute__((ext_vector_type(2))) _Float16 f16x2;
typedef __attribute__((ext_vector_type(4))) float f32x4;

// __builtin_amdgcn_cvt_pkrtz returns __fp16x2; bit-cast to our _Float16x2.
static __device__ __forceinline__ f16x2 pkrtz(float x, float y) {
    return __builtin_bit_cast(f16x2, __builtin_amdgcn_cvt_pkrtz(x, y));
}

// z = qk * (1/0.32) * log2(e)  -> exp2 domain
static constexpr float CLOG2E = 3.125f * 1.44269504088896340736f;

__global__ __launch_bounds__(256, 3)
void fattn_kernel(const float* __restrict__ Q, const float* __restrict__ K,
                  const float* __restrict__ V, float* __restrict__ O) {
    __shared__ _Float16 lk[KT][LKSTRIDE];        // K tile, row-major [n][d]
    __shared__ _Float16 lvt[DH][LVSTRIDE];       // V^T tile [d][k]
    __shared__ _Float16 lp[NWAVES][16][LPSTRIDE];// P per wave [m][k]

    const int tid  = threadIdx.x;
    const int wave = tid >> 6;
    const int lane = tid & 63;
    const int l15  = lane & 15;
    const int quad = lane >> 4;

    // XCD-aware swizzle: all 32 Q-tiles of one (b,h) land on one XCD (L2 locality).
    const int blk = blockIdx.x;          // 0..2047
    const int j   = blk >> 3;            // 0..255
    const int bh  = (blk & 7) + 8 * (j >> 5);  // 0..63
    const int qt  = j & 31;              // 0..31

    const size_t base = (size_t)bh * SEQ * DH;
    const float* Qb = Q + base;
    const float* Kb = K + base;
    const float* Vb = V + base;
    float*       Ob = O + base;

    // ---- Q fragments in A-layout: A[m=l15][k=quad*8+j], k-step ks covers d=ks*32.. ----
    f16x8 qf[4];
    {
        const int qrow = qt * QT + wave * 16 + l15;
        const float* qp = Qb + (size_t)qrow * DH + quad * 8;
#pragma unroll
        for (int ks = 0; ks < 4; ++ks) {
            float4 a = *(const float4*)(qp + ks * 32);
            float4 b = *(const float4*)(qp + ks * 32 + 4);
            f16x2 p0 = pkrtz(a.x, a.y);
            f16x2 p1 = pkrtz(a.z, a.w);
            f16x2 p2 = pkrtz(b.x, b.y);
            f16x2 p3 = pkrtz(b.z, b.w);
            qf[ks] = (f16x8){p0.x, p0.y, p1.x, p1.y, p2.x, p2.y, p3.x, p3.y};
        }
    }

    f32x4 oacc[8];
#pragma unroll
    for (int g = 0; g < 8; ++g) oacc[g] = (f32x4){0.f, 0.f, 0.f, 0.f};
    float m_i[4] = {-1e30f, -1e30f, -1e30f, -1e30f};
    float l_i[4] = {0.f, 0.f, 0.f, 0.f};

    const int c4 = tid & 31;  // float4 column index (d/4)
    const int r8 = tid >> 5;  // row group: rows r8*8 .. r8*8+7

    for (int kt0 = 0; kt0 < SEQ; kt0 += KT) {
        __syncthreads();  // protect LDS tiles from previous iteration's readers

        // ---- stage K (row-major) and V (transposed via in-register 8x4 transpose) ----
        unsigned vu[8][2];
#pragma unroll
        for (int p = 0; p < 8; ++p) {
            const int r = r8 * 8 + p;
            float4 kv = *(const float4*)(Kb + (size_t)(kt0 + r) * DH + c4 * 4);
            f16x2 k0 = pkrtz(kv.x, kv.y);
            f16x2 k1 = pkrtz(kv.z, kv.w);
            *(f16x2*)&lk[r][c4 * 4]     = k0;
            *(f16x2*)&lk[r][c4 * 4 + 2] = k1;
            float4 vv = *(const float4*)(Vb + (size_t)(kt0 + r) * DH + c4 * 4);
            f16x2 v0 = pkrtz(vv.x, vv.y);
            f16x2 v1 = pkrtz(vv.z, vv.w);
            vu[p][0] = __builtin_bit_cast(unsigned, v0);
            vu[p][1] = __builtin_bit_cast(unsigned, v1);
        }
#pragma unroll
        for (int i = 0; i < 4; ++i) {   // d = c4*4 + i ; columns of V^T, 8 k's contiguous
            const int jw = i >> 1;
            unsigned w0, w1, w2, w3;
            if ((i & 1) == 0) {
                w0 = (vu[0][jw] & 0xFFFFu) | (vu[1][jw] << 16);
                w1 = (vu[2][jw] & 0xFFFFu) | (vu[3][jw] << 16);
                w2 = (vu[4][jw] & 0xFFFFu) | (vu[5][jw] << 16);
                w3 = (vu[6][jw] & 0xFFFFu) | (vu[7][jw] << 16);
            } else {
                w0 = (vu[0][jw] >> 16) | (vu[1][jw] & 0xFFFF0000u);
                w1 = (vu[2][jw] >> 16) | (vu[3][jw] & 0xFFFF0000u);
                w2 = (vu[4][jw] >> 16) | (vu[5][jw] & 0xFFFF0000u);
                w3 = (vu[6][jw] >> 16) | (vu[7][jw] & 0xFFFF0000u);
            }
            uint4 wv = {w0, w1, w2, w3};
            *(uint4*)&lvt[c4 * 4 + i][r8 * 8] = wv;
        }
        __syncthreads();

        // ---- S = Q K^T : B-frag lane reads K[n=g*16+l15][k=ks*32+quad*8 ..+8] ----
        f32x4 sacc[4];
#pragma unroll
        for (int g = 0; g < 4; ++g) sacc[g] = (f32x4){0.f, 0.f, 0.f, 0.f};
#pragma unroll
        for (int g = 0; g < 4; ++g) {
#pragma unroll
            for (int ks = 0; ks < 4; ++ks) {
                f16x8 kf = *(const f16x8*)&lk[g * 16 + l15][ks * 32 + quad * 8];
                sacc[g] = __builtin_amdgcn_mfma_f32_16x16x32_f16(qf[ks], kf, sacc[g], 0, 0, 0);
            }
        }

        // ---- online softmax (C-layout: row = quad*4+r, col = g*16+l15) ----
        float mloc[4];
#pragma unroll
        for (int r = 0; r < 4; ++r) {
            float a0 = fmaxf(sacc[0][r], sacc[1][r]);
            float a1 = fmaxf(sacc[2][r], sacc[3][r]);
            mloc[r] = fmaxf(a0, a1) * CLOG2E;
#pragma unroll
            for (int off = 1; off < 16; off <<= 1)
                mloc[r] = fmaxf(mloc[r], __shfl_xor(mloc[r], off));
        }
        float alpha[4];
#pragma unroll
        for (int r = 0; r < 4; ++r) {
            float mnew = fmaxf(m_i[r], mloc[r]);
            alpha[r] = __builtin_amdgcn_exp2f(m_i[r] - mnew);
            m_i[r] = mnew;
        }
        float ps[4][4];
#pragma unroll
        for (int g = 0; g < 4; ++g)
#pragma unroll
            for (int r = 0; r < 4; ++r)
                ps[g][r] = __builtin_amdgcn_exp2f(sacc[g][r] * CLOG2E - m_i[r]);
#pragma unroll
        for (int r = 0; r < 4; ++r) {
            float rsum = (ps[0][r] + ps[1][r]) + (ps[2][r] + ps[3][r]);
#pragma unroll
            for (int off = 1; off < 16; off <<= 1)
                rsum += __shfl_xor(rsum, off);
            l_i[r] = l_i[r] * alpha[r] + rsum;
        }
        // P -> LDS (fp16, C-layout scatter; 2-way bank alias only = free)
#pragma unroll
        for (int g = 0; g < 4; ++g)
#pragma unroll
            for (int r = 0; r < 4; ++r)
                lp[wave][quad * 4 + r][g * 16 + l15] = (_Float16)ps[g][r];
        // rescale O accumulator
#pragma unroll
        for (int g = 0; g < 8; ++g)
#pragma unroll
            for (int r = 0; r < 4; ++r)
                oacc[g][r] *= alpha[r];

        // ---- O += P V : A-frag from lp (b128), B-frag from lvt (b128) ----
        f16x8 pa0 = *(const f16x8*)&lp[wave][l15][quad * 8];
        f16x8 pa1 = *(const f16x8*)&lp[wave][l15][32 + quad * 8];
#pragma unroll
        for (int g = 0; g < 8; ++g) {
            f16x8 vb0 = *(const f16x8*)&lvt[g * 16 + l15][quad * 8];
            f16x8 vb1 = *(const f16x8*)&lvt[g * 16 + l15][32 + quad * 8];
            oacc[g] = __builtin_amdgcn_mfma_f32_16x16x32_f16(pa0, vb0, oacc[g], 0, 0, 0);
            oacc[g] = __builtin_amdgcn_mfma_f32_16x16x32_f16(pa1, vb1, oacc[g], 0, 0, 0);
        }
    }

    // ---- epilogue: O = acc / l ----
    float inv[4];
#pragma unroll
    for (int r = 0; r < 4; ++r) inv[r] = 1.0f / l_i[r];
#pragma unroll
    for (int g = 0; g < 8; ++g) {
#pragma unroll
        for (int r = 0; r < 4; ++r) {
            const int row = qt * QT + wave * 16 + quad * 4 + r;
            const int col = g * 16 + l15;
            Ob[(size_t)row * DH + col] = oacc[g][r] * inv[r];
        }
    }
}

extern "C" void kernel_launch(void* const* d_in, const int* in_sizes, int n_in,
                              void* d_out, int out_size, void* d_ws, size_t ws_size,
                              hipStream_t stream) {
    const float* Q = (const float*)d_in[0];
    const float* K = (const float*)d_in[1];
    const float* V = (const float*)d_in[2];
    float* O = (float*)d_out;
    // masks (d_in[3..5]) and dropout_p (d_in[6]) are unused per the reference.
    const int nblocks = NB * NH * (SEQ / QT);  // 64 * 32 = 2048
    fattn_kernel<<<dim3(nblocks), dim3(256), 0, stream>>>(Q, K, V, O);
}

// Round 4
// 658.162 us; speedup vs baseline: 1.7314x; 1.7314x over previous
//
#include <hip/hip_runtime.h>

#define NB 4
#define NH 16
#define SEQ 2048
#define DH 128
#define QT 128
#define KT 64
#define NTHREADS 512
#define LKS 136   /* K-tile row stride in halfs: 272 B rows, 16B-aligned, conflict-free b128 reads */

typedef __attribute__((ext_vector_type(8))) _Float16 f16x8;
typedef __attribute__((ext_vector_type(4))) _Float16 f16x4;
typedef __attribute__((ext_vector_type(2))) _Float16 f16x2;
typedef __attribute__((ext_vector_type(4))) float f32x4;

static __device__ __forceinline__ f16x2 pkrtz(float x, float y) {
    return __builtin_bit_cast(f16x2, __builtin_amdgcn_cvt_pkrtz(x, y));
}
static __device__ __forceinline__ unsigned ubits(f16x2 v) {
    return __builtin_bit_cast(unsigned, v);
}

// scale 1/0.32 and log2(e) folded into Q at load time -> QK output is already in exp2 domain
static constexpr float CLOG2E = 3.125f * 1.44269504088896340736f;

// V^T LDS swizzle: row d (128 rows x 64 keys, no pad, row = 128B = 32 dwords).
// 8-half block kb8 stored at kb8 ^ dmix(d); verified conflict-free for staging
// writes (8B per lane) and PV b64 reads.
static __device__ __forceinline__ int vt_off(int d, int kb8, int sub4) {
    int dmix = (d & 7) ^ ((d >> 3) & 7);
    return (d << 6) + ((kb8 ^ dmix) << 3) + (sub4 << 2);
}

__global__ __launch_bounds__(NTHREADS, 4)
void fattn_kernel(const float* __restrict__ Q, const float* __restrict__ K,
                  const float* __restrict__ V, float* __restrict__ O) {
    __shared__ _Float16 lk[KT][LKS];     // K tile, row-major [key][d], fp16
    __shared__ _Float16 lvt[DH * KT];    // V^T tile, swizzled, fp16

    const int tid  = threadIdx.x;
    const int wave = tid >> 6;
    const int lane = tid & 63;
    const int l15  = lane & 15;
    const int quad = lane >> 4;

    // XCD swizzle: all 16 Q-tiles of one (b,h) on one XCD (K/V L2 locality).
    const int blk = blockIdx.x;              // 0..1023
    const int j   = blk >> 3;                // 0..127
    const int bh  = (blk & 7) + 8 * (j >> 4);
    const int qt  = j & 15;

    const size_t base = (size_t)bh * SEQ * DH;
    const float* Qb = Q + base;
    const float* Kb = K + base;
    const float* Vb = V + base;
    float*       Ob = O + base;

    // ---- Q fragments, B-operand layout: lane holds Q[q = l15][d = ks*32 + quad*8 + j] ----
    // Pre-scaled by CLOG2E so S^T comes out in the exp2 domain.
    f16x8 qf[4];
    {
        const int qrow = qt * QT + wave * 16 + l15;
        const float* qp = Qb + (size_t)qrow * DH + quad * 8;
#pragma unroll
        for (int ks = 0; ks < 4; ++ks) {
            float4 a = *(const float4*)(qp + ks * 32);
            float4 b = *(const float4*)(qp + ks * 32 + 4);
            f16x2 p0 = pkrtz(a.x * CLOG2E, a.y * CLOG2E);
            f16x2 p1 = pkrtz(a.z * CLOG2E, a.w * CLOG2E);
            f16x2 p2 = pkrtz(b.x * CLOG2E, b.y * CLOG2E);
            f16x2 p3 = pkrtz(b.z * CLOG2E, b.w * CLOG2E);
            qf[ks] = (f16x8){p0.x, p0.y, p1.x, p1.y, p2.x, p2.y, p3.x, p3.y};
        }
    }

    // O accumulator: PV output C-layout: lane holds O[q = quad*4+r][d = db*16 + l15]
    f32x4 oacc[8];
#pragma unroll
    for (int db = 0; db < 8; ++db) oacc[db] = (f32x4){0.f, 0.f, 0.f, 0.f};
    float m_i = -3.0e38f;   // per-lane: softmax state of q-row = l15 (replicated over quads)
    float l_i = 0.f;

    // staging decomposition: 512 threads, K/V tile = 64 rows x 128 cols fp32
    const int c4  = tid & 31;   // float4 column
    const int r16 = tid >> 5;   // rows r16*4 .. r16*4+3

    // ---- preload tile 0 into registers ----
    float4 kpf[4], vpf[4];
    {
        const float* kp = Kb + (size_t)(r16 * 4) * DH + c4 * 4;
        const float* vp = Vb + (size_t)(r16 * 4) * DH + c4 * 4;
#pragma unroll
        for (int p = 0; p < 4; ++p) {
            kpf[p] = *(const float4*)(kp + (size_t)p * DH);
            vpf[p] = *(const float4*)(vp + (size_t)p * DH);
        }
    }

    for (int kt0 = 0; kt0 < SEQ; kt0 += KT) {
        __syncthreads();   // previous tile's readers done

        // ---- write staged regs -> LDS (cvt fp32->fp16; V transposed + swizzled) ----
        unsigned vh[4][2];
#pragma unroll
        for (int p = 0; p < 4; ++p) {
            const int r = r16 * 4 + p;
            uint2 kw;
            kw.x = ubits(pkrtz(kpf[p].x, kpf[p].y));
            kw.y = ubits(pkrtz(kpf[p].z, kpf[p].w));
            *(uint2*)&lk[r][c4 * 4] = kw;
            vh[p][0] = ubits(pkrtz(vpf[p].x, vpf[p].y));
            vh[p][1] = ubits(pkrtz(vpf[p].z, vpf[p].w));
        }
#pragma unroll
        for (int i = 0; i < 4; ++i) {        // column d = c4*4 + i, keys r16*4..+3
            const int jw = i >> 1, sh = (i & 1) * 16;
            unsigned e0 = (vh[0][jw] >> sh) & 0xFFFFu;
            unsigned e1 = (vh[1][jw] >> sh) & 0xFFFFu;
            unsigned e2 = (vh[2][jw] >> sh) & 0xFFFFu;
            unsigned e3 = (vh[3][jw] >> sh) & 0xFFFFu;
            uint2 w;
            w.x = e0 | (e1 << 16);
            w.y = e2 | (e3 << 16);
            const int d = c4 * 4 + i;
            *(uint2*)&lvt[vt_off(d, r16 >> 1, r16 & 1)] = w;
        }
        __syncthreads();

        // ---- issue next tile's K loads (latency hides under QK + softmax) ----
        const bool more = (kt0 + KT) < SEQ;
        if (more) {
            const float* kp = Kb + (size_t)(kt0 + KT + r16 * 4) * DH + c4 * 4;
#pragma unroll
            for (int p = 0; p < 4; ++p) kpf[p] = *(const float4*)(kp + (size_t)p * DH);
        }

        // ---- S^T = K . Q^T : A = K-frag (m=key), B = Q-frag (n=q) ----
        // output lane: S[q = l15][key = g*16 + quad*4 + r]  == A-frag layout for PV!
        f32x4 sacc[4];
#pragma unroll
        for (int g = 0; g < 4; ++g) sacc[g] = (f32x4){0.f, 0.f, 0.f, 0.f};
#pragma unroll
        for (int g = 0; g < 4; ++g) {
#pragma unroll
            for (int ks = 0; ks < 4; ++ks) {
                f16x8 kf = *(const f16x8*)&lk[g * 16 + l15][ks * 32 + quad * 8];
                sacc[g] = __builtin_amdgcn_mfma_f32_16x16x32_f16(kf, qf[ks], sacc[g], 0, 0, 0);
            }
        }

        // ---- online softmax: each lane owns full row q=l15 locally (16 vals) + 2 shuffles ----
        float mx = sacc[0][0];
#pragma unroll
        for (int g = 0; g < 4; ++g)
#pragma unroll
            for (int r = 0; r < 4; ++r) mx = fmaxf(mx, sacc[g][r]);
        mx = fmaxf(mx, __shfl_xor(mx, 16));
        mx = fmaxf(mx, __shfl_xor(mx, 32));
        const float mnew = fmaxf(m_i, mx);
        const float alpha = __builtin_amdgcn_exp2f(m_i - mnew);
        m_i = mnew;

        float ps[4][4];
        float rs = 0.f;
#pragma unroll
        for (int g = 0; g < 4; ++g)
#pragma unroll
            for (int r = 0; r < 4; ++r) {
                ps[g][r] = __builtin_amdgcn_exp2f(sacc[g][r] - m_i);
                rs += ps[g][r];
            }
        rs += __shfl_xor(rs, 16);
        rs += __shfl_xor(rs, 32);
        l_i = l_i * alpha + rs;

        // ---- issue next tile's V loads (latency hides under PV) ----
        if (more) {
            const float* vp = Vb + (size_t)(kt0 + KT + r16 * 4) * DH + c4 * 4;
#pragma unroll
            for (int p = 0; p < 4; ++p) vpf[p] = *(const float4*)(vp + (size_t)p * DH);
        }

        // ---- rescale O by alpha of its own rows (q = quad*4+r, fetched via shuffle) ----
        float af[4];
#pragma unroll
        for (int r = 0; r < 4; ++r) af[r] = __shfl(alpha, (lane & 48) | (quad * 4 + r));
#pragma unroll
        for (int db = 0; db < 8; ++db)
#pragma unroll
            for (int r = 0; r < 4; ++r) oacc[db][r] *= af[r];

        // ---- O += P.V via 16x16x16 mfma: A = P (in regs!), B = V^T from LDS ----
        f16x4 pf[4];
#pragma unroll
        for (int g = 0; g < 4; ++g)
            pf[g] = (f16x4){(_Float16)ps[g][0], (_Float16)ps[g][1],
                            (_Float16)ps[g][2], (_Float16)ps[g][3]};
#pragma unroll
        for (int db = 0; db < 8; ++db) {
            const int d = db * 16 + l15;
#pragma unroll
            for (int g = 0; g < 4; ++g) {
                const int kb8 = g * 2 + (quad >> 1);
                f16x4 vb = *(const f16x4*)&lvt[vt_off(d, kb8, quad & 1)];
                oacc[db] = __builtin_amdgcn_mfma_f32_16x16x16f16(pf[g], vb, oacc[db], 0, 0, 0);
            }
        }
    }

    // ---- epilogue: O = acc / l  (l_i lives at q=l15 lanes; shuffle to C-layout rows) ----
    const float inv = 1.0f / l_i;
    float invr[4];
#pragma unroll
    for (int r = 0; r < 4; ++r) invr[r] = __shfl(inv, (lane & 48) | (quad * 4 + r));
#pragma unroll
    for (int db = 0; db < 8; ++db)
#pragma unroll
        for (int r = 0; r < 4; ++r) {
            const int row = qt * QT + wave * 16 + quad * 4 + r;
            const int col = db * 16 + l15;
            Ob[(size_t)row * DH + col] = oacc[db][r] * invr[r];
        }
}

extern "C" void kernel_launch(void* const* d_in, const int* in_sizes, int n_in,
                              void* d_out, int out_size, void* d_ws, size_t ws_size,
                              hipStream_t stream) {
    const float* Q = (const float*)d_in[0];
    const float* K = (const float*)d_in[1];
    const float* V = (const float*)d_in[2];
    float* O = (float*)d_out;
    // masks (d_in[3..5]) and dropout_p (d_in[6]) unused per reference.
    const int nblocks = NB * NH * (SEQ / QT);   // 64 * 16 = 1024
    fattn_kernel<<<dim3(nblocks), dim3(NTHREADS), 0, stream>>>(Q, K, V, O);
}